// Round 13
// baseline (706.622 us; speedup 1.0000x reference)
//
#include <hip/hip_runtime.h>
#include <cstdint>
#include <cstddef>

#define NHEAD 4
#define HID 64
#define NCOL 256          // NHEAD*HID
#define INDIM 128
#define PREDDIM 16
#define RELNUM 50
#define NLAYER 3
#define ECHUNK 8192       // edges per chunk-block in bucket build
#define DSHIFT 9          // 512 dsts per bucket
#define DPB 512           // dsts per bucket (src17+type6+dstLow9 = 32 bits)
#define MAXBUCK 256       // >= ceil(N/DPB)=196; LDS hist size
#define MAXCHUNK 512      // >= ceil(E/ECHUNK)=391
#define SPLIT_BLOCKS 32   // NCOL*INDIM / 1024
#define MLP_GRID 512      // persistent: 2 blocks/CU x 256 CU, all resident
#define AGG_GRID 1792     // persistent: 7 blocks/CU (1 block/CU residency margin)

typedef _Float16 half8 __attribute__((ext_vector_type(8)));
typedef float float4v __attribute__((ext_vector_type(4)));
typedef const __attribute__((address_space(1))) void gvoid_t;
typedef __attribute__((address_space(3))) void lvoid_t;

// ---------------- node scoring MLP: DMA-staged, LDS-converted ----------------
// mlp CONVERGED at ~41us (rounds 18/20/21: three staging vehicles all land
// 41-45; this form is cleanest: no spill, conflicts 200K, VALU 20%). FROZEN.
// Codegen ledger: B-panel up-front + asm pin + unrolled ct is mandatory
// (48-VGPR collapse otherwise, rounds 13/16/17). Fragment conventions:
// A[m=lane&15][k=(lane>>4)*8+j], D col=lane&15, row=(lane>>4)*4+reg.
__global__ __launch_bounds__(256, 2) void mlp_mfma_kernel(
    const float* __restrict__ X, const _Float16* __restrict__ Wh,
    const _Float16* __restrict__ Wl, const float* __restrict__ b1,
    const float* __restrict__ W2, const float* __restrict__ b2,
    float* __restrict__ h0, int N)
{
    __shared__ float    Xf[64][128];          // 32 KB f32 stage buffer
    __shared__ _Float16 hA[4][4][64][8];      // 16 KB f16 hi (slot-XOR)
    __shared__ _Float16 lA[4][4][64][8];      // 16 KB f16 lo

    const int tid  = threadIdx.x;
    const int w    = tid >> 6;             // wave = head
    const int lane = tid & 63;
    const int n16  = lane & 15;
    const int q    = lane >> 4;

    // ---- B panel: issue loads up front, then PIN (proven form) ----
    half8 bh[4][4], bl[4][4];
    float b1v[4], w2v[4];
    #pragma unroll
    for (int ct = 0; ct < 4; ct++) {
        const int c = w * 64 + ct * 16 + n16;
        const _Float16* pb = Wh + (size_t)c * INDIM + q * 8;
        const _Float16* pl = Wl + (size_t)c * INDIM + q * 8;
        #pragma unroll
        for (int ks = 0; ks < 4; ks++) {
            bh[ct][ks] = *reinterpret_cast<const half8*>(pb + ks * 32);
            bl[ct][ks] = *reinterpret_cast<const half8*>(pl + ks * 32);
        }
        b1v[ct] = b1[c];
        w2v[ct] = W2[c];
    }
    #pragma unroll
    for (int ct = 0; ct < 4; ct++) {
        #pragma unroll
        for (int ks = 0; ks < 4; ks++)
            asm volatile("" : "+v"(bh[ct][ks]), "+v"(bl[ct][ks]));
        asm volatile("" : "+v"(b1v[ct]), "+v"(w2v[ct]));
    }

    const float bk = b2[w];
    const int ntiles = (N + 63) >> 6;

    auto stage = [&](int tile) {
        #pragma unroll
        for (int i = 0; i < 8; i++) {
            const int lds_off = i * 4096 + w * 1024 + lane * 16;
            const int row  = lds_off >> 9;               // 512 B per row
            const int scol = (lds_off & 511) ^ ((row & 7) << 4);
            const int gn = min(tile * 64 + row, N - 1);  // clamp tail
            const char* gsrc = (const char*)X + (size_t)gn * 512 + scol;
            char* ldst = (char*)(&Xf[0][0]) + lds_off;
            __builtin_amdgcn_global_load_lds((gvoid_t*)gsrc, (lvoid_t*)ldst,
                                             16, 0, 0);
        }
    };

    const int mg  = tid >> 2, sks = tid & 3;
    const int smt = mg >> 4,  sm  = mg & 15;
    const char* frow = (const char*)(&Xf[mg][0]);
    const int rswz = (mg & 7) << 4;

    auto convert = [&]() {
        #pragma unroll
        for (int qq = 0; qq < 4; qq++) {
            const int cb = sks * 128 + qq * 32;
            float4v r0 = *reinterpret_cast<const float4v*>(frow + (cb ^ rswz));
            float4v r1 = *reinterpret_cast<const float4v*>(frow + ((cb + 16) ^ rswz));
            half8 hv, lv;
            #pragma unroll
            for (int j = 0; j < 4; j++) {
                float x = r0[j];
                _Float16 hh = (_Float16)x;
                hv[j] = hh;
                lv[j] = (_Float16)((x - (float)hh) * 2048.0f);
                x = r1[j];
                hh = (_Float16)x;
                hv[4 + j] = hh;
                lv[4 + j] = (_Float16)((x - (float)hh) * 2048.0f);
            }
            const int slot = (qq * 16 + sm) ^ (2 * sks);
            *reinterpret_cast<half8*>(&hA[smt][sks][slot][0]) = hv;
            *reinterpret_cast<half8*>(&lA[smt][sks][slot][0]) = lv;
        }
    };

    int tile = blockIdx.x;
    if (tile >= ntiles) return;

    stage(tile);
    asm volatile("s_waitcnt vmcnt(0)" ::: "memory");
    __syncthreads();
    convert();
    __syncthreads();

    while (true) {
        const int nxt = tile + MLP_GRID;
        if (nxt < ntiles) stage(nxt);      // async: flies under the MFMAs

        #pragma unroll 1
        for (int mt = 0; mt < 4; mt++) {
            half8 ah[4], al[4];
            #pragma unroll
            for (int kk = 0; kk < 4; kk++) {
                const int slot = lane ^ (2 * kk);
                ah[kk] = *reinterpret_cast<const half8*>(&hA[mt][kk][slot][0]);
                al[kk] = *reinterpret_cast<const half8*>(&lA[mt][kk][slot][0]);
            }

            float s[4] = {0.f, 0.f, 0.f, 0.f};
            #pragma unroll
            for (int ct = 0; ct < 4; ct++) {
                float4v acc = (float4v){0.f,0.f,0.f,0.f};
                float4v aca = (float4v){0.f,0.f,0.f,0.f};
                float4v acb = (float4v){0.f,0.f,0.f,0.f};
                #pragma unroll
                for (int kk = 0; kk < 4; kk++) {
                    acc = __builtin_amdgcn_mfma_f32_16x16x32_f16(ah[kk], bh[ct][kk], acc, 0, 0, 0);
                    aca = __builtin_amdgcn_mfma_f32_16x16x32_f16(ah[kk], bl[ct][kk], aca, 0, 0, 0);
                    acb = __builtin_amdgcn_mfma_f32_16x16x32_f16(al[kk], bh[ct][kk], acb, 0, 0, 0);
                }
                #pragma unroll
                for (int r = 0; r < 4; r++) {
                    float v = acc[r] + (aca[r] + acb[r]) * (1.0f / 2048.0f) + b1v[ct];
                    s[r] += fmaxf(v, 0.f) * w2v[ct];
                }
            }

            #pragma unroll
            for (int r = 0; r < 4; r++) {
                float v = s[r];
                v += __shfl_down(v, 8, 16);
                v += __shfl_down(v, 4, 16);
                v += __shfl_down(v, 2, 16);
                v += __shfl_down(v, 1, 16);
                if (n16 == 0) {
                    int node = tile * 64 + mt * 16 + q * 4 + r;
                    if (node < N) h0[(size_t)node * NHEAD + w] = v + bk;
                }
            }
        }

        if (nxt >= ntiles) break;

        asm volatile("s_waitcnt vmcnt(0)" ::: "memory");  // DMA landed
        __syncthreads();
        convert();
        __syncthreads();
        tile = nxt;
    }
}

// ---------------- fused: bucket count | attn table | W1 split ----------------
// Round-6 measured: fusion worth ~3-4us. Table block also zeroes the agg
// grid-barrier counter (workspace is poisoned, not zeroed, by the harness).
__global__ __launch_bounds__(1024) void bucket_count_fused_kernel(
    const int* __restrict__ dst, int* __restrict__ blockhist, int E,
    int nbuck, int nb,
    const float* __restrict__ rel_emb, const float* __restrict__ W_pred,
    float* __restrict__ wtab,
    const float* __restrict__ W1, _Float16* __restrict__ Wh,
    _Float16* __restrict__ Wl, int* __restrict__ bar_cnt)
{
    __shared__ int hist[MAXBUCK];
    const int tid = threadIdx.x;
    const int bx  = blockIdx.x;

    if (bx < nb) {
        if (tid < MAXBUCK) hist[tid] = 0;
        __syncthreads();
        const int base = bx * ECHUNK;
        const int end  = min(base + ECHUNK, E);
        const int nvec = (end - base) >> 2;
        const int4* d4p = reinterpret_cast<const int4*>(dst + base);
        for (int g = tid; g < nvec; g += 1024) {
            int4 d = d4p[g];
            atomicAdd(&hist[d.x >> DSHIFT], 1);
            atomicAdd(&hist[d.y >> DSHIFT], 1);
            atomicAdd(&hist[d.z >> DSHIFT], 1);
            atomicAdd(&hist[d.w >> DSHIFT], 1);
        }
        for (int i = base + (nvec << 2) + tid; i < end; i += 1024)
            atomicAdd(&hist[dst[i] >> DSHIFT], 1);
        __syncthreads();
        if (tid < nbuck) blockhist[(size_t)tid * nb + bx] = hist[tid];
    } else if (bx == nb) {
        if (tid == 1022) *bar_cnt = 0;         // init agg grid barrier
        const int idx = tid;
        if (idx < NLAYER * RELNUM * NHEAD) {
            int h = idx & 3;
            int qq = idx >> 2;
            int t = qq % RELNUM;
            int l = qq / RELNUM;
            float acc = 0.f;
            #pragma unroll
            for (int p = 0; p < PREDDIM; p++)
                acc = fmaf(rel_emb[t * PREDDIM + p],
                           W_pred[l * PREDDIM * NHEAD + p * NHEAD + h], acc);
            float e = (acc >= 0.f) ? acc : 0.2f * acc;
            wtab[idx] = __expf(e);
        }
    } else {
        // W1 hi/lo split: fp32 = hi + lo/2048 (lo x2048 keeps f16 normal)
        const int i = (bx - nb - 1) * 1024 + tid;   // NCOL*INDIM = 32768
        float v = W1[i];
        _Float16 h = (_Float16)v;
        Wh[i] = h;
        Wl[i] = (_Float16)((v - (float)h) * 2048.0f);
    }
}

// one block per bucket: exclusive scan over its nb chunk counts (nb<=512)
__global__ __launch_bounds__(512) void scan_chunks_kernel(
    const int* __restrict__ blockhist, int* __restrict__ blockbase,
    int* __restrict__ bucket_size, int nb)
{
    __shared__ int s[MAXCHUNK];
    const int b = blockIdx.x;
    const int t = threadIdx.x;
    int v = (t < nb) ? blockhist[(size_t)b * nb + t] : 0;
    s[t] = v;
    __syncthreads();
    for (int off = 1; off < MAXCHUNK; off <<= 1) {
        int u = (t >= off) ? s[t - off] : 0;
        __syncthreads();
        s[t] += u;
        __syncthreads();
    }
    if (t < nb) blockbase[(size_t)b * nb + t] = s[t] - v;   // excl. within bucket
    if (t == MAXCHUNK - 1) bucket_size[b] = s[t];
}

// one small block: exclusive scan of bucket sizes (nbuck <= 256)
__global__ __launch_bounds__(256) void scan_buckets_kernel(
    const int* __restrict__ bucket_size, int* __restrict__ bucket_start, int nbuck)
{
    __shared__ int s[256];
    const int t = threadIdx.x;
    int v = (t < nbuck) ? bucket_size[t] : 0;
    s[t] = v;
    __syncthreads();
    for (int off = 1; off < 256; off <<= 1) {
        int u = (t >= off) ? s[t - off] : 0;
        __syncthreads();
        s[t] += u;
        __syncthreads();
    }
    if (t < nbuck) bucket_start[t] = s[t] - v;
}

__global__ __launch_bounds__(1024) void bucket_scatter_kernel(
    const int* __restrict__ src, const int* __restrict__ dst,
    const int* __restrict__ types, const int* __restrict__ blockbase,
    const int* __restrict__ bucket_start, int* __restrict__ bucketed,
    int E, int nbuck, int nb)
{
    __shared__ int lbase[MAXBUCK];
    __shared__ int cur[MAXBUCK];
    const int tid = threadIdx.x;
    if (tid < MAXBUCK) {
        lbase[tid] = (tid < nbuck)
            ? blockbase[(size_t)tid * nb + blockIdx.x] + bucket_start[tid] : 0;
        cur[tid] = 0;
    }
    __syncthreads();
    const int base = blockIdx.x * ECHUNK;
    const int end  = min(base + ECHUNK, E);
    const int nvec = (end - base) >> 2;
    const int4* s4p = reinterpret_cast<const int4*>(src + base);
    const int4* d4p = reinterpret_cast<const int4*>(dst + base);
    const int4* t4p = reinterpret_cast<const int4*>(types + base);
    for (int g = tid; g < nvec; g += 1024) {
        int4 sv = s4p[g], dv = d4p[g], tv = t4p[g];
        int b, r;
        // src(0..16) | type(17..22) | dstLow(23..31) - sign bit ok, masked on use
        b = dv.x >> DSHIFT; r = atomicAdd(&cur[b], 1);
        bucketed[lbase[b] + r] = sv.x | (tv.x << 17) | ((dv.x & (DPB - 1)) << 23);
        b = dv.y >> DSHIFT; r = atomicAdd(&cur[b], 1);
        bucketed[lbase[b] + r] = sv.y | (tv.y << 17) | ((dv.y & (DPB - 1)) << 23);
        b = dv.z >> DSHIFT; r = atomicAdd(&cur[b], 1);
        bucketed[lbase[b] + r] = sv.z | (tv.z << 17) | ((dv.z & (DPB - 1)) << 23);
        b = dv.w >> DSHIFT; r = atomicAdd(&cur[b], 1);
        bucketed[lbase[b] + r] = sv.w | (tv.w << 17) | ((dv.w & (DPB - 1)) << 23);
    }
    for (int i = base + (nvec << 2) + tid; i < end; i += 1024) {
        int d = dst[i];
        int b = d >> DSHIFT;
        int r = atomicAdd(&cur[b], 1);
        bucketed[lbase[b] + r] = src[i] | (types[i] << 17) | ((d & (DPB - 1)) << 23);
    }
}

// 1024 threads; scan section runs on first DPB=512 threads.
__global__ __launch_bounds__(1024) void bucket_to_csr_kernel(
    const int* __restrict__ bucket_start, const int* __restrict__ bucket_size,
    const int* __restrict__ bucketed, int* __restrict__ sorted,
    int* __restrict__ row_start, int* __restrict__ deg, int N)
{
    __shared__ int cnt[DPB];
    __shared__ int sc[DPB];
    __shared__ int rs[DPB];
    __shared__ int cur[DPB];
    const int tid = threadIdx.x;
    const int b   = blockIdx.x;
    const int d0  = b << DSHIFT;
    const int nd  = min(DPB, N - d0);
    const int s0  = bucket_start[b];
    const int ne  = bucket_size[b];

    if (tid < DPB) { cnt[tid] = 0; cur[tid] = 0; }
    __syncthreads();
    for (int i = tid; i < ne; i += 1024)
        atomicAdd(&cnt[((unsigned)bucketed[s0 + i] >> 23) & (DPB - 1)], 1);
    __syncthreads();
    int v = 0;
    if (tid < DPB) { v = cnt[tid]; sc[tid] = v; }
    __syncthreads();
    for (int off = 1; off < DPB; off <<= 1) {
        int u = (tid < DPB && tid >= off) ? sc[tid - off] : 0;
        __syncthreads();
        if (tid < DPB) sc[tid] += u;
        __syncthreads();
    }
    if (tid < DPB) {
        int ex = sc[tid] - v;
        rs[tid] = s0 + ex;
        if (tid < nd) {
            row_start[d0 + tid] = s0 + ex;
            deg[d0 + tid] = v;
        }
    }
    __syncthreads();
    for (int i = tid; i < ne; i += 1024) {
        int pk = bucketed[s0 + i];
        int d  = ((unsigned)pk >> 23) & (DPB - 1);
        int r  = atomicAdd(&cur[d], 1);
        sorted[rs[d] + r] = pk & 0x7FFFFF;   // src | type<<17
    }
}

// ---------------- fused 3-layer aggregation (persistent + grid barriers) ----
// Round-23: agg x3 (est ~100-115us combined, never visible in top-5) fused
// into ONE persistent kernel. Grid AGG_GRID=1792 = 7 blocks/CU (1 block/CU
// margin under the 8/CU cap); __launch_bounds__(256,8) caps VGPR at 64 so
// co-residency is guaranteed -> counting grid barrier is deadlock-free.
// Device-scope release/acquire (G16) makes hs/hs2 writes visible across
// XCDs between layers. Inner edge loop = round-11 stride-4 form (measured
// best; round-12's int4 variant regressed). Removes 2 dispatch gaps and
// exposes agg's true cost in the top-5 table.
__device__ __forceinline__ void grid_barrier(int* cnt, int* gen, int nb)
{
    __shared__ int sg;
    __syncthreads();
    if (threadIdx.x == 0)
        sg = __hip_atomic_load(gen, __ATOMIC_RELAXED, __HIP_MEMORY_SCOPE_AGENT);
    __syncthreads();
    const int g0 = sg;
    if (threadIdx.x == 0) {
        __threadfence();                                   // release our stores
        if (atomicAdd(cnt, 1) == nb - 1) {
            __hip_atomic_store(cnt, 0, __ATOMIC_RELAXED, __HIP_MEMORY_SCOPE_AGENT);
            __hip_atomic_fetch_add(gen, 1, __ATOMIC_RELEASE, __HIP_MEMORY_SCOPE_AGENT);
        } else {
            while (__hip_atomic_load(gen, __ATOMIC_ACQUIRE, __HIP_MEMORY_SCOPE_AGENT) == g0)
                __builtin_amdgcn_s_sleep(16);
        }
        __threadfence();                                   // acquire others'
    }
    __syncthreads();
}

__global__ __launch_bounds__(256, 8) void agg_fused_kernel(
    const int* __restrict__ row_start, const int* __restrict__ deg,
    const int* __restrict__ sorted, const float* __restrict__ wtab,
    const float* __restrict__ h0, float* __restrict__ hs,
    float* __restrict__ hs2, float* __restrict__ out,
    const float* __restrict__ centrality, const float* __restrict__ gamma,
    const float* __restrict__ beta, int* __restrict__ bar_cnt,
    int* __restrict__ bar_gen, int N)
{
    __shared__ float4 wt4[RELNUM];
    const int tid = threadIdx.x;
    const int j   = tid & 3;
    const int nchunk = (N + 63) >> 6;

    const float g0v = gamma[0], g1v = gamma[1], g2v = gamma[2], g3v = gamma[3];
    const float be0 = beta[0],  be1 = beta[1],  be2 = beta[2],  be3 = beta[3];

    for (int l = 0; l < NLAYER; l++) {
        // load this layer's weight table (prev layer's readers are past the
        // grid barrier, which ends in __syncthreads)
        for (int i = tid; i < RELNUM; i += 256)
            wt4[i] = reinterpret_cast<const float4*>(wtab + l * RELNUM * NHEAD)[i];
        __syncthreads();

        const float* hin  = (l == 0) ? h0  : (l == 1) ? hs  : hs2;
        float*       hout = (l == 0) ? hs  : (l == 1) ? hs2 : out;

        for (int c = blockIdx.x; c < nchunk; c += AGG_GRID) {
            const int d = c * 64 + (tid >> 2);
            if (d < N) {
                int b = row_start[d], n = deg[d];
                float n0 = 0.f, n1 = 0.f, n2 = 0.f, n3 = 0.f;
                float d0 = 0.f, d1 = 0.f, d2 = 0.f, d3 = 0.f;
                if (l == 0) {
                    for (int i = j; i < n; i += 4) {
                        int pk = sorted[b + i];
                        int s = pk & 0x1FFFF;
                        int t = pk >> 17;
                        float4 w4 = wt4[t];
                        float4 h4 = *reinterpret_cast<const float4*>(hin + (size_t)s * NHEAD);
                        n0 = fmaf(w4.x, h4.x, n0); n1 = fmaf(w4.y, h4.y, n1);
                        n2 = fmaf(w4.z, h4.z, n2); n3 = fmaf(w4.w, h4.w, n3);
                        d0 += w4.x; d1 += w4.y; d2 += w4.z; d3 += w4.w;
                    }
                } else {
                    for (int i = j; i < n; i += 4) {
                        int pk = sorted[b + i];
                        int s = pk & 0x1FFFF;
                        int t = pk >> 17;
                        float4 w4 = wt4[t];
                        float hv = hin[s];
                        n0 = fmaf(w4.x, hv, n0); n1 = fmaf(w4.y, hv, n1);
                        n2 = fmaf(w4.z, hv, n2); n3 = fmaf(w4.w, hv, n3);
                        d0 += w4.x; d1 += w4.y; d2 += w4.z; d3 += w4.w;
                    }
                }

                #pragma unroll
                for (int k = 1; k <= 2; k <<= 1) {
                    n0 += __shfl_xor(n0, k); n1 += __shfl_xor(n1, k);
                    n2 += __shfl_xor(n2, k); n3 += __shfl_xor(n3, k);
                    d0 += __shfl_xor(d0, k); d1 += __shfl_xor(d1, k);
                    d2 += __shfl_xor(d2, k); d3 += __shfl_xor(d3, k);
                }

                if (j == 0) {
                    float r0 = (n > 0) ? fmaxf(n0 / d0, 0.f) : 0.f;
                    float r1 = (n > 0) ? fmaxf(n1 / d1, 0.f) : 0.f;
                    float r2 = (n > 0) ? fmaxf(n2 / d2, 0.f) : 0.f;
                    float r3 = (n > 0) ? fmaxf(n3 / d3, 0.f) : 0.f;
                    if (l == 2) {
                        float cv = centrality[d];
                        r0 *= (cv * g0v + be0);
                        r1 *= (cv * g1v + be1);
                        r2 *= (cv * g2v + be2);
                        r3 *= (cv * g3v + be3);
                    }
                    float m = (r0 + r1 + r2 + r3) * 0.25f;
                    if (l < 2) hout[d] = m;
                    else       hout[d] = (m > 0.f) ? m : 0.01f * m;
                }
            }
        }

        if (l < NLAYER - 1)
            grid_barrier(bar_cnt, bar_gen, AGG_GRID);
    }
}

// ---------------- launch ----------------
extern "C" void kernel_launch(void* const* d_in, const int* in_sizes, int n_in,
                              void* d_out, int out_size, void* d_ws, size_t ws_size,
                              hipStream_t stream)
{
    const float* X          = (const float*)d_in[0];
    const float* centrality = (const float*)d_in[1];
    const float* W1         = (const float*)d_in[2];
    const float* b1         = (const float*)d_in[3];
    const float* W2         = (const float*)d_in[4];
    const float* b2         = (const float*)d_in[5];
    const float* rel_emb    = (const float*)d_in[6];
    const float* W_pred     = (const float*)d_in[7];
    const float* gamma      = (const float*)d_in[8];
    const float* beta       = (const float*)d_in[9];
    const int*   edge_types = (const int*)d_in[10];
    const int*   src        = (const int*)d_in[11];
    const int*   dst        = (const int*)d_in[12];
    float* out = (float*)d_out;

    const int N = in_sizes[1];
    const int E = in_sizes[10];
    const int nbuck = (N + DPB - 1) / DPB;
    const int eb = (E + ECHUNK - 1) / ECHUNK;

    char* ws = (char*)d_ws;
    size_t off = 0;
    auto alloc = [&](size_t bytes) -> void* {
        void* p = ws + off;
        off = (off + bytes + 255) & ~(size_t)255;
        return p;
    };
    int*   deg       = (int*)alloc((size_t)N * 4);
    int*   row_start = (int*)alloc((size_t)N * 4);
    int*   bsize     = (int*)alloc((size_t)MAXBUCK * 4);
    int*   bstart    = (int*)alloc((size_t)MAXBUCK * 4);
    int*   blockhist = (int*)alloc((size_t)nbuck * eb * 4);
    int*   blockbase = (int*)alloc((size_t)nbuck * eb * 4);
    int*   bucketed  = (int*)alloc((size_t)E * 4);
    int*   sorted    = (int*)alloc((size_t)E * 4);
    float* wtab      = (float*)alloc((size_t)NLAYER * RELNUM * NHEAD * 4);
    float* h0        = (float*)alloc((size_t)N * NHEAD * 4);
    float* hs        = (float*)alloc((size_t)N * 4);
    float* hs2       = (float*)alloc((size_t)N * 4);
    _Float16* Wh     = (_Float16*)alloc((size_t)NCOL * INDIM * 2);
    _Float16* Wl     = (_Float16*)alloc((size_t)NCOL * INDIM * 2);
    int*   bar_cnt   = (int*)alloc(4);
    int*   bar_gen   = (int*)alloc(4);
    (void)ws_size; (void)n_in; (void)out_size;

    bucket_count_fused_kernel<<<eb + 1 + SPLIT_BLOCKS, 1024, 0, stream>>>(
        dst, blockhist, E, nbuck, eb, rel_emb, W_pred, wtab, W1, Wh, Wl,
        bar_cnt);
    scan_chunks_kernel<<<nbuck, MAXCHUNK, 0, stream>>>(blockhist, blockbase, bsize, eb);
    scan_buckets_kernel<<<1, 256, 0, stream>>>(bsize, bstart, nbuck);
    bucket_scatter_kernel<<<eb, 1024, 0, stream>>>(src, dst, edge_types, blockbase,
                                                   bstart, bucketed, E, nbuck, eb);
    bucket_to_csr_kernel<<<nbuck, 1024, 0, stream>>>(bstart, bsize, bucketed, sorted,
                                                     row_start, deg, N);

    mlp_mfma_kernel<<<MLP_GRID, 256, 0, stream>>>(X, Wh, Wl, b1, W2, b2, h0, N);

    agg_fused_kernel<<<AGG_GRID, 256, 0, stream>>>(
        row_start, deg, sorted, wtab, h0, hs, hs2, out,
        centrality, gamma, beta, bar_cnt, bar_gen, N);
}

// Round 14
// 270.873 us; speedup vs baseline: 2.6087x; 2.6087x over previous
//
#include <hip/hip_runtime.h>
#include <cstdint>
#include <cstddef>

#define NHEAD 4
#define HID 64
#define NCOL 256          // NHEAD*HID
#define INDIM 128
#define PREDDIM 16
#define RELNUM 50
#define NLAYER 3
#define ECHUNK 8192       // edges per chunk-block in bucket build
#define DSHIFT 9          // 512 dsts per bucket
#define DPB 512           // dsts per bucket (src17+type6+dstLow9 = 32 bits)
#define MAXBUCK 256       // >= ceil(N/DPB)=196; LDS hist size
#define MAXCHUNK 512      // >= ceil(E/ECHUNK)=391
#define SPLIT_BLOCKS 32   // NCOL*INDIM / 1024
#define MLP_GRID 512      // persistent: 2 blocks/CU x 256 CU, all resident

typedef _Float16 half8 __attribute__((ext_vector_type(8)));
typedef float float4v __attribute__((ext_vector_type(4)));
typedef const __attribute__((address_space(1))) void gvoid_t;
typedef __attribute__((address_space(3))) void lvoid_t;

// ---------------- node scoring MLP: DMA-staged, LDS-converted ----------------
// Round-24: FULL REVERT to the round-11 measured-best configuration
// (274.5us; round-8's 273.1 within noise). Ledger additions from rounds
// 12/13: (d) int4 agg loads regress (+5us — gather-bound, not load-bound);
// (e) fused scan (threadfence+spin) regresses; (f) ANY __launch_bounds__
// min-waves >= 3 collapses codegen on ANY kernel in this TU (mlp: rounds
// 13/16 -> 48 VGPR; agg: round 23 -> 16 VGPR, 537us). mlp CONVERGED at
// ~41us (rounds 18/20/21). FROZEN. Codegen ledger: B-panel up-front + asm
// pin + unrolled ct is mandatory. Fragment conventions:
// A[m=lane&15][k=(lane>>4)*8+j], D col=lane&15, row=(lane>>4)*4+reg.
__global__ __launch_bounds__(256, 2) void mlp_mfma_kernel(
    const float* __restrict__ X, const _Float16* __restrict__ Wh,
    const _Float16* __restrict__ Wl, const float* __restrict__ b1,
    const float* __restrict__ W2, const float* __restrict__ b2,
    float* __restrict__ h0, int N)
{
    __shared__ float    Xf[64][128];          // 32 KB f32 stage buffer
    __shared__ _Float16 hA[4][4][64][8];      // 16 KB f16 hi (slot-XOR)
    __shared__ _Float16 lA[4][4][64][8];      // 16 KB f16 lo

    const int tid  = threadIdx.x;
    const int w    = tid >> 6;             // wave = head
    const int lane = tid & 63;
    const int n16  = lane & 15;
    const int q    = lane >> 4;

    // ---- B panel: issue loads up front, then PIN (proven form) ----
    half8 bh[4][4], bl[4][4];
    float b1v[4], w2v[4];
    #pragma unroll
    for (int ct = 0; ct < 4; ct++) {
        const int c = w * 64 + ct * 16 + n16;
        const _Float16* pb = Wh + (size_t)c * INDIM + q * 8;
        const _Float16* pl = Wl + (size_t)c * INDIM + q * 8;
        #pragma unroll
        for (int ks = 0; ks < 4; ks++) {
            bh[ct][ks] = *reinterpret_cast<const half8*>(pb + ks * 32);
            bl[ct][ks] = *reinterpret_cast<const half8*>(pl + ks * 32);
        }
        b1v[ct] = b1[c];
        w2v[ct] = W2[c];
    }
    #pragma unroll
    for (int ct = 0; ct < 4; ct++) {
        #pragma unroll
        for (int ks = 0; ks < 4; ks++)
            asm volatile("" : "+v"(bh[ct][ks]), "+v"(bl[ct][ks]));
        asm volatile("" : "+v"(b1v[ct]), "+v"(w2v[ct]));
    }

    const float bk = b2[w];
    const int ntiles = (N + 63) >> 6;

    // ---- DMA stage: 32KB f32 tile; linear LDS dest (wave-uniform base +
    // lane*16), global col pre-swizzled by ^((row&7)<<4) ----
    auto stage = [&](int tile) {
        #pragma unroll
        for (int i = 0; i < 8; i++) {
            const int lds_off = i * 4096 + w * 1024 + lane * 16;
            const int row  = lds_off >> 9;               // 512 B per row
            const int scol = (lds_off & 511) ^ ((row & 7) << 4);
            const int gn = min(tile * 64 + row, N - 1);  // clamp tail
            const char* gsrc = (const char*)X + (size_t)gn * 512 + scol;
            char* ldst = (char*)(&Xf[0][0]) + lds_off;
            __builtin_amdgcn_global_load_lds((gvoid_t*)gsrc, (lvoid_t*)ldst,
                                             16, 0, 0);
        }
    };

    // convert role: thread = (row mg, 32-col chunk sks)
    const int mg  = tid >> 2, sks = tid & 3;
    const int smt = mg >> 4,  sm  = mg & 15;
    const char* frow = (const char*)(&Xf[mg][0]);
    const int rswz = (mg & 7) << 4;

    auto convert = [&]() {
        #pragma unroll
        for (int qq = 0; qq < 4; qq++) {
            const int cb = sks * 128 + qq * 32;
            float4v r0 = *reinterpret_cast<const float4v*>(frow + (cb ^ rswz));
            float4v r1 = *reinterpret_cast<const float4v*>(frow + ((cb + 16) ^ rswz));
            half8 hv, lv;
            #pragma unroll
            for (int j = 0; j < 4; j++) {
                float x = r0[j];
                _Float16 hh = (_Float16)x;
                hv[j] = hh;
                lv[j] = (_Float16)((x - (float)hh) * 2048.0f);
                x = r1[j];
                hh = (_Float16)x;
                hv[4 + j] = hh;
                lv[4 + j] = (_Float16)((x - (float)hh) * 2048.0f);
            }
            const int slot = (qq * 16 + sm) ^ (2 * sks);
            *reinterpret_cast<half8*>(&hA[smt][sks][slot][0]) = hv;
            *reinterpret_cast<half8*>(&lA[smt][sks][slot][0]) = lv;
        }
    };

    int tile = blockIdx.x;
    if (tile >= ntiles) return;

    // ---- prologue: DMA tile 0, convert into f16 buffers ----
    stage(tile);
    asm volatile("s_waitcnt vmcnt(0)" ::: "memory");
    __syncthreads();
    convert();
    __syncthreads();

    while (true) {
        const int nxt = tile + MLP_GRID;
        if (nxt < ntiles) stage(nxt);      // async: flies under the MFMAs

        // ---- compute this tile: pure {ds_read_b128 -> MFMA} ----
        #pragma unroll 1
        for (int mt = 0; mt < 4; mt++) {
            half8 ah[4], al[4];
            #pragma unroll
            for (int kk = 0; kk < 4; kk++) {
                const int slot = lane ^ (2 * kk);
                ah[kk] = *reinterpret_cast<const half8*>(&hA[mt][kk][slot][0]);
                al[kk] = *reinterpret_cast<const half8*>(&lA[mt][kk][slot][0]);
            }

            float s[4] = {0.f, 0.f, 0.f, 0.f};
            #pragma unroll
            for (int ct = 0; ct < 4; ct++) {
                float4v acc = (float4v){0.f,0.f,0.f,0.f};
                float4v aca = (float4v){0.f,0.f,0.f,0.f};
                float4v acb = (float4v){0.f,0.f,0.f,0.f};
                #pragma unroll
                for (int kk = 0; kk < 4; kk++) {
                    acc = __builtin_amdgcn_mfma_f32_16x16x32_f16(ah[kk], bh[ct][kk], acc, 0, 0, 0);
                    aca = __builtin_amdgcn_mfma_f32_16x16x32_f16(ah[kk], bl[ct][kk], aca, 0, 0, 0);
                    acb = __builtin_amdgcn_mfma_f32_16x16x32_f16(al[kk], bh[ct][kk], acb, 0, 0, 0);
                }
                #pragma unroll
                for (int r = 0; r < 4; r++) {
                    float v = acc[r] + (aca[r] + acb[r]) * (1.0f / 2048.0f) + b1v[ct];
                    s[r] += fmaxf(v, 0.f) * w2v[ct];
                }
            }

            #pragma unroll
            for (int r = 0; r < 4; r++) {
                float v = s[r];
                v += __shfl_down(v, 8, 16);
                v += __shfl_down(v, 4, 16);
                v += __shfl_down(v, 2, 16);
                v += __shfl_down(v, 1, 16);
                if (n16 == 0) {
                    int node = tile * 64 + mt * 16 + q * 4 + r;
                    if (node < N) h0[(size_t)node * NHEAD + w] = v + bk;
                }
            }
        }

        if (nxt >= ntiles) break;

        asm volatile("s_waitcnt vmcnt(0)" ::: "memory");  // DMA landed
        __syncthreads();                    // all done reading hA/lA + Xf ready
        convert();                          // f32buf -> f16 bufs, once/element
        __syncthreads();
        tile = nxt;
    }
}

// ---------------- fused: bucket count | attn table | W1 split ----------------
// Measured round 6: fusion worth ~3-4us (removes two serial dispatches).
__global__ __launch_bounds__(1024) void bucket_count_fused_kernel(
    const int* __restrict__ dst, int* __restrict__ blockhist, int E,
    int nbuck, int nb,
    const float* __restrict__ rel_emb, const float* __restrict__ W_pred,
    float* __restrict__ wtab,
    const float* __restrict__ W1, _Float16* __restrict__ Wh,
    _Float16* __restrict__ Wl)
{
    __shared__ int hist[MAXBUCK];
    const int tid = threadIdx.x;
    const int bx  = blockIdx.x;

    if (bx < nb) {
        if (tid < MAXBUCK) hist[tid] = 0;
        __syncthreads();
        const int base = bx * ECHUNK;
        const int end  = min(base + ECHUNK, E);
        const int nvec = (end - base) >> 2;
        const int4* d4p = reinterpret_cast<const int4*>(dst + base);
        for (int g = tid; g < nvec; g += 1024) {
            int4 d = d4p[g];
            atomicAdd(&hist[d.x >> DSHIFT], 1);
            atomicAdd(&hist[d.y >> DSHIFT], 1);
            atomicAdd(&hist[d.z >> DSHIFT], 1);
            atomicAdd(&hist[d.w >> DSHIFT], 1);
        }
        for (int i = base + (nvec << 2) + tid; i < end; i += 1024)
            atomicAdd(&hist[dst[i] >> DSHIFT], 1);
        __syncthreads();
        if (tid < nbuck) blockhist[(size_t)tid * nb + bx] = hist[tid];
    } else if (bx == nb) {
        const int idx = tid;
        if (idx < NLAYER * RELNUM * NHEAD) {
            int h = idx & 3;
            int qq = idx >> 2;
            int t = qq % RELNUM;
            int l = qq / RELNUM;
            float acc = 0.f;
            #pragma unroll
            for (int p = 0; p < PREDDIM; p++)
                acc = fmaf(rel_emb[t * PREDDIM + p],
                           W_pred[l * PREDDIM * NHEAD + p * NHEAD + h], acc);
            float e = (acc >= 0.f) ? acc : 0.2f * acc;
            wtab[idx] = __expf(e);
        }
    } else {
        // W1 hi/lo split: fp32 = hi + lo/2048 (lo x2048 keeps f16 normal)
        const int i = (bx - nb - 1) * 1024 + tid;   // NCOL*INDIM = 32768
        float v = W1[i];
        _Float16 h = (_Float16)v;
        Wh[i] = h;
        Wl[i] = (_Float16)((v - (float)h) * 2048.0f);
    }
}

// one block per bucket: exclusive scan over its nb chunk counts (nb<=512)
__global__ __launch_bounds__(512) void scan_chunks_kernel(
    const int* __restrict__ blockhist, int* __restrict__ blockbase,
    int* __restrict__ bucket_size, int nb)
{
    __shared__ int s[MAXCHUNK];
    const int b = blockIdx.x;
    const int t = threadIdx.x;
    int v = (t < nb) ? blockhist[(size_t)b * nb + t] : 0;
    s[t] = v;
    __syncthreads();
    for (int off = 1; off < MAXCHUNK; off <<= 1) {
        int u = (t >= off) ? s[t - off] : 0;
        __syncthreads();
        s[t] += u;
        __syncthreads();
    }
    if (t < nb) blockbase[(size_t)b * nb + t] = s[t] - v;   // excl. within bucket
    if (t == MAXCHUNK - 1) bucket_size[b] = s[t];
}

// one small block: exclusive scan of bucket sizes (nbuck <= 256)
__global__ __launch_bounds__(256) void scan_buckets_kernel(
    const int* __restrict__ bucket_size, int* __restrict__ bucket_start, int nbuck)
{
    __shared__ int s[256];
    const int t = threadIdx.x;
    int v = (t < nbuck) ? bucket_size[t] : 0;
    s[t] = v;
    __syncthreads();
    for (int off = 1; off < 256; off <<= 1) {
        int u = (t >= off) ? s[t - off] : 0;
        __syncthreads();
        s[t] += u;
        __syncthreads();
    }
    if (t < nbuck) bucket_start[t] = s[t] - v;
}

__global__ __launch_bounds__(1024) void bucket_scatter_kernel(
    const int* __restrict__ src, const int* __restrict__ dst,
    const int* __restrict__ types, const int* __restrict__ blockbase,
    const int* __restrict__ bucket_start, int* __restrict__ bucketed,
    int E, int nbuck, int nb)
{
    __shared__ int lbase[MAXBUCK];
    __shared__ int cur[MAXBUCK];
    const int tid = threadIdx.x;
    if (tid < MAXBUCK) {
        lbase[tid] = (tid < nbuck)
            ? blockbase[(size_t)tid * nb + blockIdx.x] + bucket_start[tid] : 0;
        cur[tid] = 0;
    }
    __syncthreads();
    const int base = blockIdx.x * ECHUNK;
    const int end  = min(base + ECHUNK, E);
    const int nvec = (end - base) >> 2;
    const int4* s4p = reinterpret_cast<const int4*>(src + base);
    const int4* d4p = reinterpret_cast<const int4*>(dst + base);
    const int4* t4p = reinterpret_cast<const int4*>(types + base);
    for (int g = tid; g < nvec; g += 1024) {
        int4 sv = s4p[g], dv = d4p[g], tv = t4p[g];
        int b, r;
        // src(0..16) | type(17..22) | dstLow(23..31) - sign bit ok, masked on use
        b = dv.x >> DSHIFT; r = atomicAdd(&cur[b], 1);
        bucketed[lbase[b] + r] = sv.x | (tv.x << 17) | ((dv.x & (DPB - 1)) << 23);
        b = dv.y >> DSHIFT; r = atomicAdd(&cur[b], 1);
        bucketed[lbase[b] + r] = sv.y | (tv.y << 17) | ((dv.y & (DPB - 1)) << 23);
        b = dv.z >> DSHIFT; r = atomicAdd(&cur[b], 1);
        bucketed[lbase[b] + r] = sv.z | (tv.z << 17) | ((dv.z & (DPB - 1)) << 23);
        b = dv.w >> DSHIFT; r = atomicAdd(&cur[b], 1);
        bucketed[lbase[b] + r] = sv.w | (tv.w << 17) | ((dv.w & (DPB - 1)) << 23);
    }
    for (int i = base + (nvec << 2) + tid; i < end; i += 1024) {
        int d = dst[i];
        int b = d >> DSHIFT;
        int r = atomicAdd(&cur[b], 1);
        bucketed[lbase[b] + r] = src[i] | (types[i] << 17) | ((d & (DPB - 1)) << 23);
    }
}

// 1024 threads; scan section runs on first DPB=512 threads.
__global__ __launch_bounds__(1024) void bucket_to_csr_kernel(
    const int* __restrict__ bucket_start, const int* __restrict__ bucket_size,
    const int* __restrict__ bucketed, int* __restrict__ sorted,
    int* __restrict__ row_start, int* __restrict__ deg, int N)
{
    __shared__ int cnt[DPB];
    __shared__ int sc[DPB];
    __shared__ int rs[DPB];
    __shared__ int cur[DPB];
    const int tid = threadIdx.x;
    const int b   = blockIdx.x;
    const int d0  = b << DSHIFT;
    const int nd  = min(DPB, N - d0);
    const int s0  = bucket_start[b];
    const int ne  = bucket_size[b];

    if (tid < DPB) { cnt[tid] = 0; cur[tid] = 0; }
    __syncthreads();
    for (int i = tid; i < ne; i += 1024)
        atomicAdd(&cnt[((unsigned)bucketed[s0 + i] >> 23) & (DPB - 1)], 1);
    __syncthreads();
    int v = 0;
    if (tid < DPB) { v = cnt[tid]; sc[tid] = v; }
    __syncthreads();
    for (int off = 1; off < DPB; off <<= 1) {
        int u = (tid < DPB && tid >= off) ? sc[tid - off] : 0;
        __syncthreads();
        if (tid < DPB) sc[tid] += u;
        __syncthreads();
    }
    if (tid < DPB) {
        int ex = sc[tid] - v;
        rs[tid] = s0 + ex;
        if (tid < nd) {
            row_start[d0 + tid] = s0 + ex;
            deg[d0 + tid] = v;
        }
    }
    __syncthreads();
    for (int i = tid; i < ne; i += 1024) {
        int pk = bucketed[s0 + i];
        int d  = ((unsigned)pk >> 23) & (DPB - 1);
        int r  = atomicAdd(&cur[d], 1);
        sorted[rs[d] + r] = pk & 0x7FFFFF;   // src | type<<17
    }
}

// ---------------- per-layer aggregation (edge-split quad) ----------------
// Round-7 measured: edge-split (4E->E visits) was time-neutral -> agg is
// latency/issue-bound. Round-12's int4 variant and round-13's fused
// variant both regressed; this stride-4 form is the measured best.
template <int MODE>
__global__ __launch_bounds__(256) void agg_kernel(
    const int* __restrict__ row_start, const int* __restrict__ deg,
    const int* __restrict__ sorted, const float* __restrict__ wt_l,
    const float* __restrict__ hin, float* __restrict__ hout,
    const float* __restrict__ centrality, const float* __restrict__ gamma,
    const float* __restrict__ beta, int N)
{
    __shared__ float4 wt4[RELNUM];          // [type] -> 4 heads
    for (int i = threadIdx.x; i < RELNUM; i += blockDim.x)
        wt4[i] = reinterpret_cast<const float4*>(wt_l)[i];
    __syncthreads();

    int gid = blockIdx.x * blockDim.x + threadIdx.x;
    int d = gid >> 2, j = gid & 3;
    if (d >= N) return;

    int b = row_start[d], n = deg[d];
    float n0 = 0.f, n1 = 0.f, n2 = 0.f, n3 = 0.f;
    float d0 = 0.f, d1 = 0.f, d2 = 0.f, d3 = 0.f;
    for (int i = j; i < n; i += 4) {
        int pk = sorted[b + i];
        int s = pk & 0x1FFFF;
        int t = pk >> 17;
        float4 w4 = wt4[t];
        if (MODE == 0) {
            float4 h4 = *reinterpret_cast<const float4*>(hin + (size_t)s * NHEAD);
            n0 = fmaf(w4.x, h4.x, n0); n1 = fmaf(w4.y, h4.y, n1);
            n2 = fmaf(w4.z, h4.z, n2); n3 = fmaf(w4.w, h4.w, n3);
        } else {
            float hv = hin[s];
            n0 = fmaf(w4.x, hv, n0); n1 = fmaf(w4.y, hv, n1);
            n2 = fmaf(w4.z, hv, n2); n3 = fmaf(w4.w, hv, n3);
        }
        d0 += w4.x; d1 += w4.y; d2 += w4.z; d3 += w4.w;
    }

    #pragma unroll
    for (int k = 1; k <= 2; k <<= 1) {
        n0 += __shfl_xor(n0, k); n1 += __shfl_xor(n1, k);
        n2 += __shfl_xor(n2, k); n3 += __shfl_xor(n3, k);
        d0 += __shfl_xor(d0, k); d1 += __shfl_xor(d1, k);
        d2 += __shfl_xor(d2, k); d3 += __shfl_xor(d3, k);
    }

    if (j == 0) {
        float r0 = (n > 0) ? fmaxf(n0 / d0, 0.f) : 0.f;
        float r1 = (n > 0) ? fmaxf(n1 / d1, 0.f) : 0.f;
        float r2 = (n > 0) ? fmaxf(n2 / d2, 0.f) : 0.f;
        float r3 = (n > 0) ? fmaxf(n3 / d3, 0.f) : 0.f;
        if (MODE == 2) {
            float c = centrality[d];
            r0 *= (c * gamma[0] + beta[0]);
            r1 *= (c * gamma[1] + beta[1]);
            r2 *= (c * gamma[2] + beta[2]);
            r3 *= (c * gamma[3] + beta[3]);
        }
        float m = (r0 + r1 + r2 + r3) * 0.25f;
        if (MODE < 2) hout[d] = m;
        else          hout[d] = (m > 0.f) ? m : 0.01f * m;
    }
}

// ---------------- launch ----------------
extern "C" void kernel_launch(void* const* d_in, const int* in_sizes, int n_in,
                              void* d_out, int out_size, void* d_ws, size_t ws_size,
                              hipStream_t stream)
{
    const float* X          = (const float*)d_in[0];
    const float* centrality = (const float*)d_in[1];
    const float* W1         = (const float*)d_in[2];
    const float* b1         = (const float*)d_in[3];
    const float* W2         = (const float*)d_in[4];
    const float* b2         = (const float*)d_in[5];
    const float* rel_emb    = (const float*)d_in[6];
    const float* W_pred     = (const float*)d_in[7];
    const float* gamma      = (const float*)d_in[8];
    const float* beta       = (const float*)d_in[9];
    const int*   edge_types = (const int*)d_in[10];
    const int*   src        = (const int*)d_in[11];
    const int*   dst        = (const int*)d_in[12];
    float* out = (float*)d_out;

    const int N = in_sizes[1];
    const int E = in_sizes[10];
    const int nbuck = (N + DPB - 1) / DPB;
    const int eb = (E + ECHUNK - 1) / ECHUNK;

    char* ws = (char*)d_ws;
    size_t off = 0;
    auto alloc = [&](size_t bytes) -> void* {
        void* p = ws + off;
        off = (off + bytes + 255) & ~(size_t)255;
        return p;
    };
    int*   deg       = (int*)alloc((size_t)N * 4);
    int*   row_start = (int*)alloc((size_t)N * 4);
    int*   bsize     = (int*)alloc((size_t)MAXBUCK * 4);
    int*   bstart    = (int*)alloc((size_t)MAXBUCK * 4);
    int*   blockhist = (int*)alloc((size_t)nbuck * eb * 4);
    int*   blockbase = (int*)alloc((size_t)nbuck * eb * 4);
    int*   bucketed  = (int*)alloc((size_t)E * 4);
    int*   sorted    = (int*)alloc((size_t)E * 4);
    float* wtab      = (float*)alloc((size_t)NLAYER * RELNUM * NHEAD * 4);
    float* h0        = (float*)alloc((size_t)N * NHEAD * 4);
    float* hs        = (float*)alloc((size_t)N * 4);
    float* hs2       = (float*)alloc((size_t)N * 4);
    _Float16* Wh     = (_Float16*)alloc((size_t)NCOL * INDIM * 2);
    _Float16* Wl     = (_Float16*)alloc((size_t)NCOL * INDIM * 2);
    (void)ws_size; (void)n_in; (void)out_size;

    bucket_count_fused_kernel<<<eb + 1 + SPLIT_BLOCKS, 1024, 0, stream>>>(
        dst, blockhist, E, nbuck, eb, rel_emb, W_pred, wtab, W1, Wh, Wl);
    scan_chunks_kernel<<<nbuck, MAXCHUNK, 0, stream>>>(blockhist, blockbase, bsize, eb);
    scan_buckets_kernel<<<1, 256, 0, stream>>>(bsize, bstart, nbuck);
    bucket_scatter_kernel<<<eb, 1024, 0, stream>>>(src, dst, edge_types, blockbase,
                                                   bstart, bucketed, E, nbuck, eb);
    bucket_to_csr_kernel<<<nbuck, 1024, 0, stream>>>(bstart, bsize, bucketed, sorted,
                                                     row_start, deg, N);

    mlp_mfma_kernel<<<MLP_GRID, 256, 0, stream>>>(X, Wh, Wl, b1, W2, b2, h0, N);

    const int ab = (N * NHEAD + 255) / 256;
    agg_kernel<0><<<ab, 256, 0, stream>>>(row_start, deg, sorted, wtab + 0 * RELNUM * NHEAD,
                                          h0, hs, nullptr, nullptr, nullptr, N);
    agg_kernel<1><<<ab, 256, 0, stream>>>(row_start, deg, sorted, wtab + 1 * RELNUM * NHEAD,
                                          hs, hs2, nullptr, nullptr, nullptr, N);
    agg_kernel<2><<<ab, 256, 0, stream>>>(row_start, deg, sorted, wtab + 2 * RELNUM * NHEAD,
                                          hs2, out, centrality, gamma, beta, N);
}